// Round 3
// baseline (123.802 us; speedup 1.0000x reference)
//
#include <hip/hip_runtime.h>

#define NSTEP  730
#define NGRID  2000
#define PRECSf 1e-5f

__device__ __forceinline__ float fast_exp2(float v) { return __builtin_amdgcn_exp2f(v); }
__device__ __forceinline__ float fast_log2(float v) { return __builtin_amdgcn_logf(v); }

// broadcast lane I (0..15) of each 16-lane row to the whole row. BitMode
// swizzle: new_lane = (lane & 0x10) | I  (within each 32-lane half).
template<int I>
__device__ __forceinline__ float bcast16(float v) {
    return __int_as_float(__builtin_amdgcn_ds_swizzle(__float_as_int(v), (I << 5) | 0x10));
}

// prefix-sum within each 16-lane row via DPP row_shr; lane 15 = row total.
__device__ __forceinline__ float row_psum(float v) {
    int t;
    t = __builtin_amdgcn_update_dpp(0, __float_as_int(v), 0x111, 0xF, 0xF, true); v += __int_as_float(t);
    t = __builtin_amdgcn_update_dpp(0, __float_as_int(v), 0x112, 0xF, 0xF, true); v += __int_as_float(t);
    t = __builtin_amdgcn_update_dpp(0, __float_as_int(v), 0x114, 0xF, 0xF, true); v += __int_as_float(t);
    t = __builtin_amdgcn_update_dpp(0, __float_as_int(v), 0x118, 0xF, 0xF, true); v += __int_as_float(t);
    return v;
}

struct Par {
    float TT, cfmax, cfmaxTT, cfrXcf, cfrTT, CWH;
    float beta, betaC, FC, betaet, betaetC;
    float PERC, omK0, k0uzl, omK1, K2;
};

// Issue 3 loads (P,T,E of step T0_+m for this cell) via inline asm: the
// results are forced live in VGPRs; asm volatile cannot be sunk to uses.
#define ISSUE(P_, T_, E_, T0_) do {                                            \
    int tl_ = (T0_) + m; tl_ = tl_ < NSTEP ? tl_ : NSTEP - 1;                  \
    const float* a_ = xg + (size_t)tl_ * (NGRID * 3);                          \
    asm volatile("global_load_dword %0, %3, off\n\t"                          \
                 "global_load_dword %1, %3, off offset:4\n\t"                  \
                 "global_load_dword %2, %3, off offset:8"                      \
                 : "=&v"(P_), "=&v"(T_), "=&v"(E_) : "v"(a_) : "memory");      \
} while (0)

// Counted wait; ties the buffer regs so consumers are data-dependent on it.
// N=16: the 3 loads are older than the 16 stores of the previous chunk
// (vmcnt retires in order on CDNA), so outstanding<=16 => loads landed.
#define WAIT3(P_, T_, E_, N_)                                                  \
    asm volatile("s_waitcnt vmcnt(" #N_ ")"                                    \
                 : "+v"(P_), "+v"(T_), "+v"(E_) :: "memory")

template<int I, int NS>
__device__ __forceinline__ void steps(float Pv, float Tv, float Ev, int t0,
                                      float& SP, float& MW, float& SM,
                                      float& SUZ, float& SLZ,
                                      const Par& c, float* out, int g, bool lastlane)
{
    if constexpr (I < NS) {
        const float Pt = bcast16<I>(Pv);
        const float Tt = bcast16<I>(Tv);
        const float Et = bcast16<I>(Ev);

        // snow/melt subsystem (independent of SM/SUZ/SLZ)
        const float snow    = (Tt < c.TT) ? Pt : 0.0f;
        const float rain    = Pt - snow;
        const float meltcap = fmaxf(fmaf(c.cfmax,   Tt, -c.cfmaxTT), 0.0f);
        const float refrcap = fmaxf(fmaf(-c.cfrXcf, Tt,  c.cfrTT ), 0.0f);
        const float SP1  = SP + snow;
        const float SP2  = fmaxf(SP1 - meltcap, 0.0f);   // melt = SP1-SP2
        const float melt = SP1 - SP2;
        const float MW1  = MW + melt;
        const float MW2  = fmaxf(MW1 - refrcap, 0.0f);   // refr = MW1-MW2
        const float refr = MW1 - MW2;
        SP = SP2 + refr;
        const float tosoil = fmaxf(fmaf(-c.CWH, SP, MW2), 0.0f);
        MW = MW2 - tosoil;

        // soil moisture (the serial critical chain)
        const float A    = rain + tosoil;
        const float SMpA = SM + A;
        const float sw   = fast_exp2(fmaf(c.beta, fast_log2(SM), c.betaC)); // (SM/FC)^beta, <=1 since SM<=FC
        const float SM1  = fmaf(-A, sw, SMpA);           // SM + A*(1-sw)
        const float SM2  = fminf(SM1, c.FC);
        const float inflow = SMpA - SM2;                 // recharge + excess (telescoped)
        const float e2   = fast_exp2(fmaf(c.betaet, fast_log2(SM2), c.betaetC));
        const float Ete  = Et * e2;
        // SM' = max(SM2 - min(SM2, Et*e2, Et), PRECS) = max3(SM2-Ete, SM2-Et, PRECS)
        SM = fmaxf(fmaxf(SM2 - Ete, SM2 - Et), PRECSf);

        // routing (hangs off inflow; never feeds back)
        const float SUZ1 = SUZ + inflow;
        const float PERCv = fminf(SUZ1, c.PERC);
        const float SUZ2 = SUZ1 - PERCv;
        const float SUZ3 = fminf(SUZ2, fmaf(c.omK0, SUZ2, c.k0uzl)); // SUZ2 - K0*max(SUZ2-UZL,0)
        const float SUZ4 = c.omK1 * SUZ3;
        SUZ = SUZ4;
        const float SLZ1 = SLZ + PERCv;
        const float Q2   = c.K2 * SLZ1;
        SLZ = SLZ1 - Q2;
        float qs = (SUZ2 - SUZ4) + Q2;                   // Q0+Q1+Q2 telescoped

        qs = row_psum(qs);
        if (lastlane) out[(size_t)(t0 + I) * NGRID + g] = qs * 0.0625f;

        steps<I + 1, NS>(Pv, Tv, Ev, t0, SP, MW, SM, SUZ, SLZ, c, out, g, lastlane);
    }
}

__global__ __launch_bounds__(64, 1)
void hbv_kernel(const float* __restrict__ x,
                const float* __restrict__ params,
                float* __restrict__ out)
{
    const int tid = blockIdx.x * 64 + threadIdx.x;
    const int g = tid >> 4;
    const int m = tid & 15;
    const bool lastlane = (m == 15);

    const float lo[13] = {1.f,50.f,0.05f,0.01f,0.001f,0.2f,0.f,0.f,-2.5f,0.5f,0.f,0.f,0.3f};
    const float hi[13] = {6.f,1000.f,0.9f,0.5f,0.2f,1.f,10.f,100.f,2.5f,10.f,0.1f,0.2f,5.f};
    float p[13];
    const float* pg = params + ((size_t)g * 13) * 16 + m;
#pragma unroll
    for (int i = 0; i < 13; ++i) p[i] = lo[i] + pg[(size_t)i * 16] * (hi[i] - lo[i]);

    Par c;
    c.TT      = p[8];
    c.cfmax   = p[9];
    c.cfmaxTT = p[9] * p[8];
    c.cfrXcf  = p[10] * p[9];
    c.cfrTT   = c.cfrXcf * p[8];
    c.CWH     = p[11];
    c.beta    = p[0];
    c.betaC   = -p[0] * fast_log2(p[1]);          // beta*log2(1/FC)
    c.FC      = p[1];
    c.betaet  = p[12];
    c.betaetC = -p[12] * fast_log2(p[5] * p[1]);  // betaet*log2(1/(LP*FC))
    c.PERC    = p[6];
    c.omK0    = 1.0f - p[2];
    c.k0uzl   = p[2] * p[7];
    c.omK1    = 1.0f - p[3];
    c.K2      = p[4];

    float SP = 0.001f, MW = 0.001f, SM = 0.001f, SUZ = 0.001f, SLZ = 0.001f;
    const float* xg = x + (size_t)g * 3;

    float Pa, Ta, Ea, Pb, Tb, Eb;

    // chunk 0 (cold wait), prefetch chunk 1
    ISSUE(Pa, Ta, Ea, 0);
    WAIT3(Pa, Ta, Ea, 0);
    ISSUE(Pb, Tb, Eb, 16);
    steps<0, 16>(Pa, Ta, Ea, 0, SP, MW, SM, SUZ, SLZ, c, out, g, lastlane);

    // chunks 1..42 in parity pairs (21 iterations x 2 chunks)
    for (int cc = 0; cc < 21; ++cc) {
        const int t0 = 16 + cc * 32;
        WAIT3(Pb, Tb, Eb, 16);
        ISSUE(Pa, Ta, Ea, t0 + 16);
        steps<0, 16>(Pb, Tb, Eb, t0, SP, MW, SM, SUZ, SLZ, c, out, g, lastlane);
        WAIT3(Pa, Ta, Ea, 16);
        ISSUE(Pb, Tb, Eb, t0 + 32);
        steps<0, 16>(Pa, Ta, Ea, t0 + 16, SP, MW, SM, SUZ, SLZ, c, out, g, lastlane);
    }

    // chunks 43, 44, 45 (tail: 10 steps)
    WAIT3(Pb, Tb, Eb, 16);
    ISSUE(Pa, Ta, Ea, 704);
    steps<0, 16>(Pb, Tb, Eb, 688, SP, MW, SM, SUZ, SLZ, c, out, g, lastlane);
    WAIT3(Pa, Ta, Ea, 16);
    ISSUE(Pb, Tb, Eb, 720);
    steps<0, 16>(Pa, Ta, Ea, 704, SP, MW, SM, SUZ, SLZ, c, out, g, lastlane);
    WAIT3(Pb, Tb, Eb, 16);
    steps<0, 10>(Pb, Tb, Eb, 720, SP, MW, SM, SUZ, SLZ, c, out, g, lastlane);
}

extern "C" void kernel_launch(void* const* d_in, const int* in_sizes, int n_in,
                              void* d_out, int out_size, void* d_ws, size_t ws_size,
                              hipStream_t stream)
{
    const float* x      = (const float*)d_in[0];
    const float* params = (const float*)d_in[1];
    float* out          = (float*)d_out;

    hipLaunchKernelGGL(hbv_kernel, dim3(500), dim3(64), 0, stream, x, params, out);
}

// Round 5
// 120.048 us; speedup vs baseline: 1.0313x; 1.0313x over previous
//
#include <hip/hip_runtime.h>

#define NSTEP  730
#define NGRID  2000
#define PRECSf 1e-5f

#define GLOBAL_AS __attribute__((address_space(1)))
#define LDS_AS    __attribute__((address_space(3)))

__device__ __forceinline__ float fast_exp2(float v) { return __builtin_amdgcn_exp2f(v); }
__device__ __forceinline__ float fast_log2(float v) { return __builtin_amdgcn_logf(v); }

// prefix-sum within each 16-lane row via DPP row_shr; lane 15 = row total.
__device__ __forceinline__ float row_psum(float v) {
    int t;
    t = __builtin_amdgcn_update_dpp(0, __float_as_int(v), 0x111, 0xF, 0xF, true); v += __int_as_float(t);
    t = __builtin_amdgcn_update_dpp(0, __float_as_int(v), 0x112, 0xF, 0xF, true); v += __int_as_float(t);
    t = __builtin_amdgcn_update_dpp(0, __float_as_int(v), 0x114, 0xF, 0xF, true); v += __int_as_float(t);
    t = __builtin_amdgcn_update_dpp(0, __float_as_int(v), 0x118, 0xF, 0xF, true); v += __int_as_float(t);
    return v;
}

struct Par {
    float TT, cfmax, cfmaxTT, cfrXcf, cfrTT, CWH;
    float beta, betaC, FC, betaet, betaetC;
    float PERC, omK0, k0uzl, omK1, K2;
};

// compiler-level memory fence: pins VMEM program order (no instruction emitted)
#define MEMFENCE() asm volatile("" ::: "memory")
// counted HW wait; "memory" stops ds_reads being hoisted above it
#define WAITV(N)  asm volatile("s_waitcnt vmcnt(" #N ")" ::: "memory")

// ---- snow step I of a chunk (SP/MW recurrence), runs ONE CHUNK AHEAD ----
// reads x from LDS: layout xs[buf][i*16 + crow*4 + {0,1,2}] = P,T,E
template<int I>
__device__ __forceinline__ void snow1(const float* xb, int crow,
        float& SP, float& MW,
        float (&A)[16], float (&Ets)[16], float (&cEts)[16], const Par& c)
{
    const float4 v = *reinterpret_cast<const float4*>(xb + I * 16 + crow * 4);
    const float Pt = v.x, Tt = v.y, Ex = v.z;

    const float snow    = (Tt < c.TT) ? Pt : 0.0f;
    const float rain    = Pt - snow;
    const float meltcap = fmaxf(fmaf(c.cfmax,   Tt, -c.cfmaxTT), 0.0f);
    const float refrcap = fmaxf(fmaf(-c.cfrXcf, Tt,  c.cfrTT ), 0.0f);
    const float SP1  = SP + snow;
    const float SP2  = fmaxf(SP1 - meltcap, 0.0f);
    const float melt = SP1 - SP2;
    const float MW1  = MW + melt;
    const float MW2  = fmaxf(MW1 - refrcap, 0.0f);
    const float refr = MW1 - MW2;
    SP = SP2 + refr;
    const float tosoil = fmaxf(fmaf(-c.CWH, SP, MW2), 0.0f);
    MW = MW2 - tosoil;
    A[I]    = rain + tosoil;
    Ets[I]  = Ex;
    cEts[I] = c.betaetC + fast_log2(Ex);   // fold Et into the evap exponent
}

// ---- soil+routing step I, consuming the pipelined A/Et/cEt (R3-proven math) ----
template<int I>
__device__ __forceinline__ void soil1(const float (&A)[16], const float (&Ets)[16],
        const float (&cEts)[16],
        float& SM, float& SUZ, float& SLZ, const Par& c,
        int t0, float* __restrict__ out, int g, bool lastlane)
{
    const float Ac  = A[I];
    const float Et  = Ets[I];
    const float cEt = cEts[I];

    const float SMpA = SM + Ac;
    const float sw   = fast_exp2(fmaf(c.beta, fast_log2(SM), c.betaC)); // (SM/FC)^beta <= 1
    const float SM1  = fmaf(-Ac, sw, SMpA);
    const float SM2  = fminf(SM1, c.FC);
    const float inflow = SMpA - SM2;                        // recharge + excess
    const float Ete  = fast_exp2(fmaf(c.betaet, fast_log2(SM2), cEt)); // Et*(SM2/LPFC)^bet
    SM = fmaxf(fmaxf(SM2 - Ete, SM2 - Et), PRECSf);         // max3

    const float SUZ1  = SUZ + inflow;
    const float PERCv = fminf(SUZ1, c.PERC);
    const float SUZ2  = SUZ1 - PERCv;
    const float SUZ3  = fminf(SUZ2, fmaf(c.omK0, SUZ2, c.k0uzl));
    const float SUZ4  = c.omK1 * SUZ3;
    SUZ = SUZ4;
    const float SLZ1 = SLZ + PERCv;
    const float Q2   = c.K2 * SLZ1;
    SLZ = SLZ1 - Q2;
    float qs = (SUZ2 - SUZ4) + Q2;

    qs = row_psum(qs);
    if (lastlane) out[(size_t)(t0 + I) * NGRID + g] = qs * 0.0625f;
}

template<int I, int NS>
__device__ __forceinline__ void snow_pass(const float* xb, int crow,
        float& SP, float& MW, float (&A)[16], float (&Ets)[16], float (&cEts)[16],
        const Par& c)
{
    if constexpr (I < NS) {
        snow1<I>(xb, crow, SP, MW, A, Ets, cEts, c);
        snow_pass<I + 1, NS>(xb, crow, SP, MW, A, Ets, cEts, c);
    }
}

template<int I, int NS>
__device__ __forceinline__ void soil_pass(const float (&A)[16], const float (&Ets)[16],
        const float (&cEts)[16], float& SM, float& SUZ, float& SLZ, const Par& c,
        int t0, float* __restrict__ out, int g, bool lastlane)
{
    if constexpr (I < NS) {
        soil1<I>(A, Ets, cEts, SM, SUZ, SLZ, c, t0, out, g, lastlane);
        soil_pass<I + 1, NS>(A, Ets, cEts, SM, SUZ, SLZ, c, t0, out, g, lastlane);
    }
}

// interleaved: snow step i of chunk k+1 (from LDS) || soil step i of chunk k
template<int I, int NS>
__device__ __forceinline__ void both_pass(const float* xb, int crow,
        float& SP, float& MW,
        float (&An)[16], float (&Etn)[16], float (&cEtn)[16],
        const float (&Ac)[16], const float (&Etc)[16], const float (&cEtc)[16],
        float& SM, float& SUZ, float& SLZ, const Par& c,
        int t0, float* __restrict__ out, int g, bool lastlane)
{
    if constexpr (I < NS) {
        snow1<I>(xb, crow, SP, MW, An, Etn, cEtn, c);
        soil1<I>(Ac, Etc, cEtc, SM, SUZ, SLZ, c, t0, out, g, lastlane);
        both_pass<I + 1, NS>(xb, crow, SP, MW, An, Etn, cEtn, Ac, Etc, cEtc,
                             SM, SUZ, SLZ, c, t0, out, g, lastlane);
    }
}

__global__ __launch_bounds__(64, 1)
void hbv_kernel(const float* __restrict__ x,
                const float* __restrict__ params,
                float* __restrict__ out)
{
    // one wave per block: 4 grid cells x 16 members. No barriers needed.
    __shared__ __align__(16) float xs[2][256];   // [buf][i*16 + c*4 + comp(3=pad)]

    const int lane = threadIdx.x;        // 0..63
    const int g0   = blockIdx.x * 4;
    const int crow = lane >> 4;          // cell within block
    const int m    = lane & 15;          // ensemble member
    const int g    = g0 + crow;
    const bool lastlane = (m == 15);

    // per-lane staging source for the 4 global_load_lds per chunk:
    // instruction j stages LDS flat index j*64+lane; flat = i*16 + c*4 + comp
    const float* srcb[4];
    int ioff[4];
#pragma unroll
    for (int j = 0; j < 4; ++j) {
        const int flat = j * 64 + lane;
        const int i    = flat >> 4;
        const int cc   = (flat >> 2) & 3;
        int comp       = flat & 3; if (comp == 3) comp = 0;   // pad slot: harmless re-load
        srcb[j] = x + (size_t)(g0 + cc) * 3 + comp;
        ioff[j] = i;
    }

#define ISSUE(B, T0) do {                                                      \
    MEMFENCE();                                                                \
    _Pragma("unroll")                                                          \
    for (int j = 0; j < 4; ++j) {                                              \
        int stp = (T0) + ioff[j]; stp = stp < NSTEP ? stp : NSTEP - 1;         \
        const float* s_ = srcb[j] + (size_t)stp * (NGRID * 3);                 \
        __builtin_amdgcn_global_load_lds((const GLOBAL_AS unsigned*)s_,        \
            (LDS_AS unsigned*)&xs[B][j * 64], 4, 0, 0);                        \
    }                                                                          \
    MEMFENCE();                                                                \
} while (0)

    // --- parameter de-normalization ---
    const float lo[13] = {1.f,50.f,0.05f,0.01f,0.001f,0.2f,0.f,0.f,-2.5f,0.5f,0.f,0.f,0.3f};
    const float hi[13] = {6.f,1000.f,0.9f,0.5f,0.2f,1.f,10.f,100.f,2.5f,10.f,0.1f,0.2f,5.f};
    float p[13];
    const float* pg = params + ((size_t)g * 13) * 16 + m;
#pragma unroll
    for (int i = 0; i < 13; ++i) p[i] = lo[i] + pg[(size_t)i * 16] * (hi[i] - lo[i]);

    Par c;
    c.TT      = p[8];
    c.cfmax   = p[9];
    c.cfmaxTT = p[9] * p[8];
    c.cfrXcf  = p[10] * p[9];
    c.cfrTT   = c.cfrXcf * p[8];
    c.CWH     = p[11];
    c.beta    = p[0];
    c.betaC   = -p[0] * fast_log2(p[1]);
    c.FC      = p[1];
    c.betaet  = p[12];
    c.betaetC = -p[12] * fast_log2(p[5] * p[1]);
    c.PERC    = p[6];
    c.omK0    = 1.0f - p[2];
    c.k0uzl   = p[2] * p[7];
    c.omK1    = 1.0f - p[3];
    c.K2      = p[4];

    float SP = 0.001f, MW = 0.001f, SM = 0.001f, SUZ = 0.001f, SLZ = 0.001f;

    float Aa[16], EtA[16], cEtA[16];
    float Ab[16], EtB[16], cEtB[16];

    // prologue: stage chunks 0,1; snow chunk 0 -> Aa
    ISSUE(0, 0);
    ISSUE(1, 16);
    WAITV(4);                         // chunk 0 staged (4 oldest of 8)
    snow_pass<0, 16>(&xs[0][0], crow, SP, MW, Aa, EtA, cEtA, c);

    // body k: wait chunk k+1 staged; issue chunk k+2 into buf[k&1];
    //         snow chunk k+1 (buf[(k+1)&1]) -> AN; soil chunk k <- AC.
#define BODY_W(K, WN, AC_, ETC_, CETC_, AN_, ETN_, CETN_)                      \
    WAITV(WN);                                                                 \
    ISSUE((K) & 1, ((K) + 2) * 16);                                            \
    both_pass<0, 16>(&xs[((K) + 1) & 1][0], crow, SP, MW,                      \
                     AN_, ETN_, CETN_, AC_, ETC_, CETC_,                       \
                     SM, SUZ, SLZ, c, (K) * 16, out, g, lastlane);

    // k=0: only the 4 chunk-1 loads outstanding -> full drain
    BODY_W(0, 0, Aa, EtA, cEtA, Ab, EtB, cEtB);

    // k = 1..44 as 22 parity pairs (odd k: soil<-Ab, snow->Aa; even k: reverse)
    for (int kk = 0; kk < 22; ++kk) {
        const int k0 = 1 + kk * 2;
        BODY_W(k0,     16, Ab, EtB, cEtB, Aa, EtA, cEtA);
        BODY_W(k0 + 1, 16, Aa, EtA, cEtA, Ab, EtB, cEtB);
    }
#undef BODY_W

    // epilogue: soil chunk 45 = steps 720..729 (10 steps) from Ab
    soil_pass<0, 10>(Ab, EtB, cEtB, SM, SUZ, SLZ, c, 720, out, g, lastlane);
#undef ISSUE
}

extern "C" void kernel_launch(void* const* d_in, const int* in_sizes, int n_in,
                              void* d_out, int out_size, void* d_ws, size_t ws_size,
                              hipStream_t stream)
{
    const float* x      = (const float*)d_in[0];
    const float* params = (const float*)d_in[1];
    float* out          = (float*)d_out;

    hipLaunchKernelGGL(hbv_kernel, dim3(500), dim3(64), 0, stream, x, params, out);
}

// Round 7
// 92.072 us; speedup vs baseline: 1.3446x; 1.3039x over previous
//
#include <hip/hip_runtime.h>

#define NSTEP  730
#define NGRID  2000
#define PRECSf 1e-5f

#define GLOBAL_AS __attribute__((address_space(1)))
#define LDS_AS    __attribute__((address_space(3)))

__device__ __forceinline__ float fast_exp2(float v) { return __builtin_amdgcn_exp2f(v); }
__device__ __forceinline__ float fast_log2(float v) { return __builtin_amdgcn_logf(v); }

// prefix-sum within each 16-lane row via DPP row_shr; lane 15 = row total.
__device__ __forceinline__ float row_psum(float v) {
    int t;
    t = __builtin_amdgcn_update_dpp(0, __float_as_int(v), 0x111, 0xF, 0xF, true); v += __int_as_float(t);
    t = __builtin_amdgcn_update_dpp(0, __float_as_int(v), 0x112, 0xF, 0xF, true); v += __int_as_float(t);
    t = __builtin_amdgcn_update_dpp(0, __float_as_int(v), 0x114, 0xF, 0xF, true); v += __int_as_float(t);
    t = __builtin_amdgcn_update_dpp(0, __float_as_int(v), 0x118, 0xF, 0xF, true); v += __int_as_float(t);
    return v;
}

struct Par {
    float TT, cfmax, cfmaxTT, cfrXcf, cfrTT, CWH;
    float beta, betaC, FC, betaet, betaetC;
    float PERC, omK0, k0uzl, omK1, K2;
};

#define MEMFENCE() asm volatile("" ::: "memory")
#define WAITV(N)  asm volatile("s_waitcnt vmcnt(" #N ")" ::: "memory")

// ---- snow step I (SP/MW recurrence), runs ONE CHUNK AHEAD; x from registers ----
template<int I>
__device__ __forceinline__ void snow1(const float4 (&xv)[16],
        float& SP, float& MW,
        float (&A)[16], float (&Ets)[16], float (&cEts)[16], const Par& c)
{
    const float Pt = xv[I].x, Tt = xv[I].y, Ex = xv[I].z;

    const float snow    = (Tt < c.TT) ? Pt : 0.0f;
    const float rain    = Pt - snow;
    const float meltcap = fmaxf(fmaf(c.cfmax,   Tt, -c.cfmaxTT), 0.0f);
    const float refrcap = fmaxf(fmaf(-c.cfrXcf, Tt,  c.cfrTT ), 0.0f);
    const float SP1  = SP + snow;
    const float SP2  = fmaxf(SP1 - meltcap, 0.0f);
    const float melt = SP1 - SP2;
    const float MW1  = MW + melt;
    const float MW2  = fmaxf(MW1 - refrcap, 0.0f);
    const float refr = MW1 - MW2;
    SP = SP2 + refr;
    const float tosoil = fmaxf(fmaf(-c.CWH, SP, MW2), 0.0f);
    MW = MW2 - tosoil;
    A[I]    = rain + tosoil;
    Ets[I]  = Ex;
    cEts[I] = c.betaetC + fast_log2(Ex);
}

// ---- soil+routing step I; result into qbuf (stores batched at body end) ----
template<int I>
__device__ __forceinline__ void soil1(const float (&A)[16], const float (&Ets)[16],
        const float (&cEts)[16], float (&qbuf)[16],
        float& SM, float& SUZ, float& SLZ, const Par& c)
{
    const float Ac  = A[I];
    const float Et  = Ets[I];
    const float cEt = cEts[I];

    const float SMpA = SM + Ac;
    const float sw   = fast_exp2(fmaf(c.beta, fast_log2(SM), c.betaC)); // (SM/FC)^beta <= 1
    const float SM1  = fmaf(-Ac, sw, SMpA);
    const float SM2  = fminf(SM1, c.FC);
    const float inflow = SMpA - SM2;
    const float Ete  = fast_exp2(fmaf(c.betaet, fast_log2(SM2), cEt)); // Et*(SM2/LPFC)^bet
    SM = fmaxf(fmaxf(SM2 - Ete, SM2 - Et), PRECSf);

    const float SUZ1  = SUZ + inflow;
    const float PERCv = fminf(SUZ1, c.PERC);
    const float SUZ2  = SUZ1 - PERCv;
    const float SUZ3  = fminf(SUZ2, fmaf(c.omK0, SUZ2, c.k0uzl));
    const float SUZ4  = c.omK1 * SUZ3;
    SUZ = SUZ4;
    const float SLZ1 = SLZ + PERCv;
    const float Q2   = c.K2 * SLZ1;
    SLZ = SLZ1 - Q2;

    qbuf[I] = row_psum((SUZ2 - SUZ4) + Q2);
}

template<int I, int NS>
__device__ __forceinline__ void snow_pass(const float4 (&xv)[16],
        float& SP, float& MW, float (&A)[16], float (&Ets)[16], float (&cEts)[16],
        const Par& c)
{
    if constexpr (I < NS) {
        snow1<I>(xv, SP, MW, A, Ets, cEts, c);
        snow_pass<I + 1, NS>(xv, SP, MW, A, Ets, cEts, c);
    }
}

template<int I, int NS>
__device__ __forceinline__ void soil_pass(const float (&A)[16], const float (&Ets)[16],
        const float (&cEts)[16], float (&qbuf)[16],
        float& SM, float& SUZ, float& SLZ, const Par& c)
{
    if constexpr (I < NS) {
        soil1<I>(A, Ets, cEts, qbuf, SM, SUZ, SLZ, c);
        soil_pass<I + 1, NS>(A, Ets, cEts, qbuf, SM, SUZ, SLZ, c);
    }
}

// interleaved: soil step i of chunk k (register-only) || snow step i of chunk k+1
template<int I, int NS>
__device__ __forceinline__ void both_pass(const float4 (&xv)[16],
        float& SP, float& MW,
        float (&An)[16], float (&Etn)[16], float (&cEtn)[16],
        const float (&Ac)[16], const float (&Etc)[16], const float (&cEtc)[16],
        float (&qbuf)[16],
        float& SM, float& SUZ, float& SLZ, const Par& c)
{
    if constexpr (I < NS) {
        soil1<I>(Ac, Etc, cEtc, qbuf, SM, SUZ, SLZ, c);
        snow1<I>(xv, SP, MW, An, Etn, cEtn, c);
        both_pass<I + 1, NS>(xv, SP, MW, An, Etn, cEtn, Ac, Etc, cEtc,
                             qbuf, SM, SUZ, SLZ, c);
    }
}

// hoisted LDS->reg burst for one chunk. The two "memory"-clobber fences
// (WAITV above, ISSUE's MEMFENCE below) pin the ds_reads into this slot;
// the scalar pin anchors the loaded values against rematerialization.
#define LOAD_XV(B)                                                             \
    _Pragma("unroll")                                                          \
    for (int i = 0; i < 16; ++i)                                               \
        xv[i] = *reinterpret_cast<const float4*>(&xs[B][i * 16 + crow * 4]);   \
    asm volatile("" :: "v"(xv[0].x),  "v"(xv[1].x),  "v"(xv[2].x),             \
                       "v"(xv[3].x),  "v"(xv[4].x),  "v"(xv[5].x),             \
                       "v"(xv[6].x),  "v"(xv[7].x),  "v"(xv[8].x),             \
                       "v"(xv[9].x),  "v"(xv[10].x), "v"(xv[11].x),            \
                       "v"(xv[12].x), "v"(xv[13].x), "v"(xv[14].x),            \
                       "v"(xv[15].x))

#define STORE_Q(T0, N)                                                         \
    if (lastlane) {                                                            \
        _Pragma("unroll")                                                      \
        for (int i = 0; i < (N); ++i)                                          \
            out[(size_t)((T0) + i) * NGRID + g] = qbuf[i] * 0.0625f;           \
    }

__global__ __launch_bounds__(64, 1)
void hbv_kernel(const float* __restrict__ x,
                const float* __restrict__ params,
                float* __restrict__ out)
{
    // one wave per block: 4 grid cells x 16 members. No barriers needed.
    __shared__ __align__(16) float xs[2][256];   // [buf][i*16 + c*4 + comp(3=pad)]

    const int lane = threadIdx.x;        // 0..63
    const int g0   = blockIdx.x * 4;
    const int crow = lane >> 4;          // cell within block
    const int m    = lane & 15;          // ensemble member
    const int g    = g0 + crow;
    const bool lastlane = (m == 15);

    // per-lane staging source: instruction j stages LDS flat index j*64+lane
    const float* srcb[4];
    int ioff[4];
#pragma unroll
    for (int j = 0; j < 4; ++j) {
        const int flat = j * 64 + lane;
        const int i    = flat >> 4;
        const int cc   = (flat >> 2) & 3;
        int comp       = flat & 3; if (comp == 3) comp = 0;   // pad slot
        srcb[j] = x + (size_t)(g0 + cc) * 3 + comp;
        ioff[j] = i;
    }

#define ISSUE(B, T0) do {                                                      \
    MEMFENCE();                                                                \
    _Pragma("unroll")                                                          \
    for (int j = 0; j < 4; ++j) {                                              \
        int stp = (T0) + ioff[j]; stp = stp < NSTEP ? stp : NSTEP - 1;         \
        const float* s_ = srcb[j] + (size_t)stp * (NGRID * 3);                 \
        __builtin_amdgcn_global_load_lds((const GLOBAL_AS unsigned*)s_,        \
            (LDS_AS unsigned*)&xs[B][j * 64], 4, 0, 0);                        \
    }                                                                          \
    MEMFENCE();                                                                \
} while (0)

    // --- parameter de-normalization ---
    const float lo[13] = {1.f,50.f,0.05f,0.01f,0.001f,0.2f,0.f,0.f,-2.5f,0.5f,0.f,0.f,0.3f};
    const float hi[13] = {6.f,1000.f,0.9f,0.5f,0.2f,1.f,10.f,100.f,2.5f,10.f,0.1f,0.2f,5.f};
    float p[13];
    const float* pg = params + ((size_t)g * 13) * 16 + m;
#pragma unroll
    for (int i = 0; i < 13; ++i) p[i] = lo[i] + pg[(size_t)i * 16] * (hi[i] - lo[i]);

    Par c;
    c.TT      = p[8];
    c.cfmax   = p[9];
    c.cfmaxTT = p[9] * p[8];
    c.cfrXcf  = p[10] * p[9];
    c.cfrTT   = c.cfrXcf * p[8];
    c.CWH     = p[11];
    c.beta    = p[0];
    c.betaC   = -p[0] * fast_log2(p[1]);
    c.FC      = p[1];
    c.betaet  = p[12];
    c.betaetC = -p[12] * fast_log2(p[5] * p[1]);
    c.PERC    = p[6];
    c.omK0    = 1.0f - p[2];
    c.k0uzl   = p[2] * p[7];
    c.omK1    = 1.0f - p[3];
    c.K2      = p[4];

    float SP = 0.001f, MW = 0.001f, SM = 0.001f, SUZ = 0.001f, SLZ = 0.001f;

    float4 xv[16];
    float Aa[16], EtA[16], cEtA[16];
    float Ab[16], EtB[16], cEtB[16];
    float qbuf[16];

    // prologue: stage chunks 0,1; read chunk0 to regs; snow chunk0 -> Aa
    ISSUE(0, 0);
    ISSUE(1, 16);
    WAITV(4);                         // chunk 0 staged
    LOAD_XV(0);
    snow_pass<0, 16>(xv, SP, MW, Aa, EtA, cEtA, c);

    // body k: wait chunk k+1 staged; hoist its x to regs; issue chunk k+2;
    //         soil chunk k (AC) interleaved with snow chunk k+1 (-> AN); store q.
#define BODY_W(K, WN, AC_, ETC_, CETC_, AN_, ETN_, CETN_)                      \
    WAITV(WN);                                                                 \
    LOAD_XV(((K) + 1) & 1);                                                    \
    ISSUE((K) & 1, ((K) + 2) * 16);                                            \
    both_pass<0, 16>(xv, SP, MW, AN_, ETN_, CETN_, AC_, ETC_, CETC_,           \
                     qbuf, SM, SUZ, SLZ, c);                                   \
    STORE_Q((K) * 16, 16);

    // k=0: only chunk-1's 4 gll outstanding -> full drain
    BODY_W(0, 0, Aa, EtA, cEtA, Ab, EtB, cEtB);

    // k = 1..44 as 22 parity pairs
    for (int kk = 0; kk < 22; ++kk) {
        const int k0 = 1 + kk * 2;
        BODY_W(k0,     16, Ab, EtB, cEtB, Aa, EtA, cEtA);
        BODY_W(k0 + 1, 16, Aa, EtA, cEtA, Ab, EtB, cEtB);
    }
#undef BODY_W

    // epilogue: soil chunk 45 = steps 720..729 from Ab
    soil_pass<0, 10>(Ab, EtB, cEtB, qbuf, SM, SUZ, SLZ, c);
    STORE_Q(720, 10);
#undef ISSUE
}

extern "C" void kernel_launch(void* const* d_in, const int* in_sizes, int n_in,
                              void* d_out, int out_size, void* d_ws, size_t ws_size,
                              hipStream_t stream)
{
    const float* x      = (const float*)d_in[0];
    const float* params = (const float*)d_in[1];
    float* out          = (float*)d_out;

    hipLaunchKernelGGL(hbv_kernel, dim3(500), dim3(64), 0, stream, x, params, out);
}

// Round 8
// 83.797 us; speedup vs baseline: 1.4774x; 1.0987x over previous
//
#include <hip/hip_runtime.h>

#define NSTEP  730
#define NGRID  2000
#define PRECSf 1e-5f

#define GLOBAL_AS __attribute__((address_space(1)))
#define LDS_AS    __attribute__((address_space(3)))

__device__ __forceinline__ float fast_exp2(float v) { return __builtin_amdgcn_exp2f(v); }
__device__ __forceinline__ float fast_log2(float v) { return __builtin_amdgcn_logf(v); }
__device__ __forceinline__ float med3(float a, float b, float c) {
    return __builtin_amdgcn_fmed3f(a, b, c);
}

struct Par {
    float TT, cfmax, cfmaxTT, cfrXcf, cfrTT, CWH;
    float beta, betaC, FC, betaet, betaetC;
    float PERC, omK0, k0uzl, omK1, K2;
};

#define MEMFENCE() asm volatile("" ::: "memory")
#define WAITV(N)  asm volatile("s_waitcnt vmcnt(" #N ")" ::: "memory")

// ---- snow step I (SP/MW recurrence), runs ONE CHUNK AHEAD; x from registers ----
// med3 forms are exact: SP1,MW1 >= 0, so
//   SP2 = max(SP1 - max(mraw,0), 0) = med3(SP1 - mraw, 0, SP1)
template<int I>
__device__ __forceinline__ void snow1(const float4 (&xv)[16],
        float& SP, float& MW,
        float (&A)[16], float (&Ets)[16], float (&cEts)[16], const Par& c)
{
    const float Pt = xv[I].x, Tt = xv[I].y, Ex = xv[I].z;

    const float snow = (Tt < c.TT) ? Pt : 0.0f;
    const float rain = Pt - snow;
    const float mraw = fmaf(c.cfmax,   Tt, -c.cfmaxTT);   // unclamped melt cap
    const float rraw = fmaf(-c.cfrXcf, Tt,  c.cfrTT );    // unclamped refreeze cap
    const float SP1  = SP + snow;
    const float SP2  = med3(SP1 - mraw, 0.0f, SP1);
    const float MW1  = MW + (SP1 - SP2);                  // MW + melt
    const float MW2  = med3(MW1 - rraw, 0.0f, MW1);
    SP = SP2 + (MW1 - MW2);                               // SP2 + refreezing
    const float tosoil = fmaxf(fmaf(-c.CWH, SP, MW2), 0.0f);
    MW = MW2 - tosoil;
    A[I]    = rain + tosoil;
    Ets[I]  = Ex;
    cEts[I] = c.betaetC + fast_log2(Ex);                  // fold Et into evap exponent
}

// ---- soil+routing step I; raw q into qbuf (reduced at chunk end) ----
template<int I>
__device__ __forceinline__ void soil1(const float (&A)[16], const float (&Ets)[16],
        const float (&cEts)[16], float (&qbuf)[16],
        float& SM, float& SUZ, float& SLZ, const Par& c)
{
    const float Ac  = A[I];
    const float Et  = Ets[I];
    const float cEt = cEts[I];

    const float SMpA = SM + Ac;
    const float sw   = fast_exp2(fmaf(c.beta, fast_log2(SM), c.betaC)); // (SM/FC)^beta <= 1
    const float SM1  = fmaf(-Ac, sw, SMpA);
    const float SM2  = fminf(SM1, c.FC);
    const float inflow = SMpA - SM2;
    const float Ete  = fast_exp2(fmaf(c.betaet, fast_log2(SM2), cEt)); // Et*(SM2/LPFC)^bet
    SM = fmaxf(fmaxf(SM2 - Ete, SM2 - Et), PRECSf);       // v_max3

    const float SUZ1  = SUZ + inflow;
    const float PERCv = fminf(SUZ1, c.PERC);
    const float SUZ2  = SUZ1 - PERCv;
    const float SUZ3  = fminf(SUZ2, fmaf(c.omK0, SUZ2, c.k0uzl));
    const float SUZ4  = c.omK1 * SUZ3;
    SUZ = SUZ4;
    const float SLZ1 = SLZ + PERCv;
    const float Q2   = c.K2 * SLZ1;
    SLZ = SLZ1 - Q2;

    qbuf[I] = (SUZ2 - SUZ4) + Q2;                         // raw; no per-step reduce
}

template<int I, int NS>
__device__ __forceinline__ void snow_pass(const float4 (&xv)[16],
        float& SP, float& MW, float (&A)[16], float (&Ets)[16], float (&cEts)[16],
        const Par& c)
{
    if constexpr (I < NS) {
        snow1<I>(xv, SP, MW, A, Ets, cEts, c);
        snow_pass<I + 1, NS>(xv, SP, MW, A, Ets, cEts, c);
    }
}

template<int I, int NS>
__device__ __forceinline__ void soil_pass(const float (&A)[16], const float (&Ets)[16],
        const float (&cEts)[16], float (&qbuf)[16],
        float& SM, float& SUZ, float& SLZ, const Par& c)
{
    if constexpr (I < NS) {
        soil1<I>(A, Ets, cEts, qbuf, SM, SUZ, SLZ, c);
        soil_pass<I + 1, NS>(A, Ets, cEts, qbuf, SM, SUZ, SLZ, c);
    }
}

// interleaved: soil step i of chunk k (register-only) || snow step i of chunk k+1
template<int I, int NS>
__device__ __forceinline__ void both_pass(const float4 (&xv)[16],
        float& SP, float& MW,
        float (&An)[16], float (&Etn)[16], float (&cEtn)[16],
        const float (&Ac)[16], const float (&Etc)[16], const float (&cEtc)[16],
        float (&qbuf)[16],
        float& SM, float& SUZ, float& SLZ, const Par& c)
{
    if constexpr (I < NS) {
        soil1<I>(Ac, Etc, cEtc, qbuf, SM, SUZ, SLZ, c);
        snow1<I>(xv, SP, MW, An, Etn, cEtn, c);
        both_pass<I + 1, NS>(xv, SP, MW, An, Etn, cEtn, Ac, Etc, cEtc,
                             qbuf, SM, SUZ, SLZ, c);
    }
}

// hoisted LDS->reg burst for one chunk (fences pin it; scalar pin anchors values)
#define LOAD_XV(B)                                                             \
    _Pragma("unroll")                                                          \
    for (int i = 0; i < 16; ++i)                                               \
        xv[i] = *reinterpret_cast<const float4*>(&xs[B][i * 16 + crow * 4]);   \
    asm volatile("" :: "v"(xv[0].x),  "v"(xv[1].x),  "v"(xv[2].x),             \
                       "v"(xv[3].x),  "v"(xv[4].x),  "v"(xv[5].x),             \
                       "v"(xv[6].x),  "v"(xv[7].x),  "v"(xv[8].x),             \
                       "v"(xv[9].x),  "v"(xv[10].x), "v"(xv[11].x),            \
                       "v"(xv[12].x), "v"(xv[13].x), "v"(xv[14].x),            \
                       "v"(xv[15].x))

// chunk-end reduce: transpose 16x16 (per cell) through LDS, tree-sum, store.
// qt row-block stride 336 words: banks for (crow,m) spread, 2-way worst on reads
// of same (mm): crow 0/2 and 1/3 alias (2-way = free).
#define REDUCE_STORE(T0, N) do {                                               \
    float* qrow = &qt[crow * 336 + m * 20];                                    \
    *reinterpret_cast<float4*>(qrow + 0)  = make_float4(qbuf[0], qbuf[1], qbuf[2], qbuf[3]);   \
    *reinterpret_cast<float4*>(qrow + 4)  = make_float4(qbuf[4], qbuf[5], qbuf[6], qbuf[7]);   \
    *reinterpret_cast<float4*>(qrow + 8)  = make_float4(qbuf[8], qbuf[9], qbuf[10], qbuf[11]); \
    *reinterpret_cast<float4*>(qrow + 12) = make_float4(qbuf[12], qbuf[13], qbuf[14], qbuf[15]);\
    const float* qcol = &qt[crow * 336 + m];                                   \
    float s0 = qcol[0*20]  + qcol[1*20];                                       \
    float s1 = qcol[2*20]  + qcol[3*20];                                       \
    float s2 = qcol[4*20]  + qcol[5*20];                                       \
    float s3 = qcol[6*20]  + qcol[7*20];                                       \
    float s4 = qcol[8*20]  + qcol[9*20];                                       \
    float s5 = qcol[10*20] + qcol[11*20];                                      \
    float s6 = qcol[12*20] + qcol[13*20];                                      \
    float s7 = qcol[14*20] + qcol[15*20];                                      \
    s0 += s1; s2 += s3; s4 += s5; s6 += s7;                                    \
    s0 += s2; s4 += s6;                                                        \
    s0 += s4;                                                                  \
    if (m < (N)) out[(size_t)((T0) + m) * NGRID + g] = s0 * 0.0625f;           \
} while (0)

__global__ __launch_bounds__(64, 1)
void hbv_kernel(const float* __restrict__ x,
                const float* __restrict__ params,
                float* __restrict__ out)
{
    // one wave per block: 4 grid cells x 16 members. No barriers needed.
    __shared__ __align__(16) float xs[2][256];   // staging [buf][i*16 + c*4 + comp]
    __shared__ __align__(16) float qt[4 * 336];  // q transpose scratch

    const int lane = threadIdx.x;        // 0..63
    const int g0   = blockIdx.x * 4;
    const int crow = lane >> 4;          // cell within block
    const int m    = lane & 15;          // ensemble member
    const int g    = g0 + crow;

    // per-lane staging source: instruction j stages LDS flat index j*64+lane
    const float* srcb[4];
    int ioff[4];
#pragma unroll
    for (int j = 0; j < 4; ++j) {
        const int flat = j * 64 + lane;
        const int i    = flat >> 4;
        const int cc   = (flat >> 2) & 3;
        int comp       = flat & 3; if (comp == 3) comp = 0;   // pad slot
        srcb[j] = x + (size_t)(g0 + cc) * 3 + comp;
        ioff[j] = i;
    }

#define ISSUE(B, T0) do {                                                      \
    MEMFENCE();                                                                \
    _Pragma("unroll")                                                          \
    for (int j = 0; j < 4; ++j) {                                              \
        int stp = (T0) + ioff[j]; stp = stp < NSTEP ? stp : NSTEP - 1;         \
        const float* s_ = srcb[j] + (size_t)stp * (NGRID * 3);                 \
        __builtin_amdgcn_global_load_lds((const GLOBAL_AS unsigned*)s_,        \
            (LDS_AS unsigned*)&xs[B][j * 64], 4, 0, 0);                        \
    }                                                                          \
    MEMFENCE();                                                                \
} while (0)

    // --- parameter de-normalization ---
    const float lo[13] = {1.f,50.f,0.05f,0.01f,0.001f,0.2f,0.f,0.f,-2.5f,0.5f,0.f,0.f,0.3f};
    const float hi[13] = {6.f,1000.f,0.9f,0.5f,0.2f,1.f,10.f,100.f,2.5f,10.f,0.1f,0.2f,5.f};
    float p[13];
    const float* pg = params + ((size_t)g * 13) * 16 + m;
#pragma unroll
    for (int i = 0; i < 13; ++i) p[i] = lo[i] + pg[(size_t)i * 16] * (hi[i] - lo[i]);

    Par c;
    c.TT      = p[8];
    c.cfmax   = p[9];
    c.cfmaxTT = p[9] * p[8];
    c.cfrXcf  = p[10] * p[9];
    c.cfrTT   = c.cfrXcf * p[8];
    c.CWH     = p[11];
    c.beta    = p[0];
    c.betaC   = -p[0] * fast_log2(p[1]);
    c.FC      = p[1];
    c.betaet  = p[12];
    c.betaetC = -p[12] * fast_log2(p[5] * p[1]);
    c.PERC    = p[6];
    c.omK0    = 1.0f - p[2];
    c.k0uzl   = p[2] * p[7];
    c.omK1    = 1.0f - p[3];
    c.K2      = p[4];

    float SP = 0.001f, MW = 0.001f, SM = 0.001f, SUZ = 0.001f, SLZ = 0.001f;

    float4 xv[16];
    float Aa[16], EtA[16], cEtA[16];
    float Ab[16], EtB[16], cEtB[16];
    float qbuf[16];

    // prologue: stage chunks 0,1; read chunk0 to regs; snow chunk0 -> Aa
    ISSUE(0, 0);
    ISSUE(1, 16);
    WAITV(4);                         // chunk 0 staged
    LOAD_XV(0);
    snow_pass<0, 16>(xv, SP, MW, Aa, EtA, cEtA, c);

    // body k: wait chunk k+1 staged; hoist x to regs; issue chunk k+2;
    //         soil chunk k || snow chunk k+1; transpose-reduce + store.
#define BODY_W(K, WN, AC_, ETC_, CETC_, AN_, ETN_, CETN_)                      \
    WAITV(WN);                                                                 \
    LOAD_XV(((K) + 1) & 1);                                                    \
    ISSUE((K) & 1, ((K) + 2) * 16);                                            \
    both_pass<0, 16>(xv, SP, MW, AN_, ETN_, CETN_, AC_, ETC_, CETC_,           \
                     qbuf, SM, SUZ, SLZ, c);                                   \
    REDUCE_STORE((K) * 16, 16);

    // k=0: only chunk-1's 4 gll outstanding -> full drain
    BODY_W(0, 0, Aa, EtA, cEtA, Ab, EtB, cEtB);

    // k = 1..44 as 22 parity pairs  (WN=20: 4 gll of next chunk + 16 q-stores)
    for (int kk = 0; kk < 22; ++kk) {
        const int k0 = 1 + kk * 2;
        BODY_W(k0,     20, Ab, EtB, cEtB, Aa, EtA, cEtA);
        BODY_W(k0 + 1, 20, Aa, EtA, cEtA, Ab, EtB, cEtB);
    }
#undef BODY_W

    // epilogue: soil chunk 45 = steps 720..729 from Ab
    soil_pass<0, 10>(Ab, EtB, cEtB, qbuf, SM, SUZ, SLZ, c);
    REDUCE_STORE(720, 10);
#undef ISSUE
}

extern "C" void kernel_launch(void* const* d_in, const int* in_sizes, int n_in,
                              void* d_out, int out_size, void* d_ws, size_t ws_size,
                              hipStream_t stream)
{
    const float* x      = (const float*)d_in[0];
    const float* params = (const float*)d_in[1];
    float* out          = (float*)d_out;

    hipLaunchKernelGGL(hbv_kernel, dim3(500), dim3(64), 0, stream, x, params, out);
}